// Round 5
// baseline (284.137 us; speedup 1.0000x reference)
//
#include <hip/hip_runtime.h>
#include <hip/hip_bf16.h>
#include <math.h>

// Problem constants (reference: B=2, T=2048, D_MODEL=1024, N_HEAD=16, D_HEAD=64)
constexpr int Bb   = 2;
constexpr int T    = 2048;
constexpr int C    = 1024;
constexpr int H    = 16;
constexpr int M    = Bb * T;   // 4096 rows
constexpr int NQKV = 3 * C;    // 3072

typedef __attribute__((ext_vector_type(8))) short bf16x8;
typedef __attribute__((ext_vector_type(4))) float f32x4;

__device__ inline short f2bf(float f) {
    __hip_bfloat16 h = __float2bfloat16(f);
    return *reinterpret_cast<short*>(&h);
}

#define GLOBAL_AS __attribute__((address_space(1)))
#define LDS_AS    __attribute__((address_space(3)))

__device__ __forceinline__ void gload_lds16(const short* g, short* s) {
    __builtin_amdgcn_global_load_lds((const GLOBAL_AS void*)g, (LDS_AS void*)s, 16, 0, 0);
}

// ---------------------------------------------------------------------------
// fp32 -> bf16 elementwise
// ---------------------------------------------------------------------------
__global__ __launch_bounds__(256)
void cvt_bf16(const float* __restrict__ x, short* __restrict__ y, int n)
{
    int i = (blockIdx.x * 256 + threadIdx.x) * 4;
    if (i < n) {
        const float4 v = *(const float4*)(x + i);
        short4 s;
        s.x = f2bf(v.x); s.y = f2bf(v.y); s.z = f2bf(v.z); s.w = f2bf(v.w);
        *(short4*)(y + i) = s;
    }
}

// ---------------------------------------------------------------------------
// W[K][N] fp32  ->  Wt[N][K] bf16   (32x32 LDS tile transpose)
// ---------------------------------------------------------------------------
__global__ __launch_bounds__(256)
void transpose_cvt(const float* __restrict__ W, short* __restrict__ Wt, int K, int N)
{
    __shared__ float tile[32][33];
    const int n0 = blockIdx.x * 32, k0 = blockIdx.y * 32;
    const int tx = threadIdx.x, ty = threadIdx.y;   // 32 x 8
#pragma unroll
    for (int i = 0; i < 32; i += 8)
        tile[ty + i][tx] = W[(size_t)(k0 + ty + i) * N + n0 + tx];
    __syncthreads();
#pragma unroll
    for (int i = 0; i < 32; i += 8)
        Wt[(size_t)(n0 + ty + i) * K + k0 + tx] = f2bf(tile[tx][ty + i]);
}

// ---------------------------------------------------------------------------
// QKV GEMM: out[M,N] = A @ Bt^T + bias   (128x128 tile, BK=32, m97 staging)
// (unchanged from round 4 — validated)
// ---------------------------------------------------------------------------
__global__ __launch_bounds__(256)
void gemm_mfma(const short* __restrict__ A, const short* __restrict__ Bt,
               const float* __restrict__ bias, short* __restrict__ outp,
               int Ndim, int Kdim)
{
    __shared__ __align__(16) short As[128 * 32];
    __shared__ __align__(16) short Bs[128 * 32];

    const int tid = threadIdx.x;
    const int w   = tid >> 6;
    const int l   = tid & 63;
    const int lk  = l & 15;
    const int lq  = l >> 4;
    const int m0  = blockIdx.y * 128, n0 = blockIdx.x * 128;
    const int mw  = (w >> 1) * 64, nw = (w & 1) * 64;

    const int srow = w * 16 + (l >> 2);
    const int scol = (l & 3) * 8;
    short* asdst0 = &As[w * 512];
    short* asdst1 = &As[2048 + w * 512];
    short* bsdst0 = &Bs[w * 512];
    short* bsdst1 = &Bs[2048 + w * 512];

    f32x4 acc[4][4];
#pragma unroll
    for (int i = 0; i < 4; ++i)
#pragma unroll
        for (int j = 0; j < 4; ++j) acc[i][j] = (f32x4){0.f, 0.f, 0.f, 0.f};

    for (int k0 = 0; k0 < Kdim; k0 += 32) {
        __syncthreads();
        gload_lds16(A  + (size_t)(m0 + srow)      * Kdim + k0 + scol, asdst0);
        gload_lds16(A  + (size_t)(m0 + 64 + srow) * Kdim + k0 + scol, asdst1);
        gload_lds16(Bt + (size_t)(n0 + srow)      * Kdim + k0 + scol, bsdst0);
        gload_lds16(Bt + (size_t)(n0 + 64 + srow) * Kdim + k0 + scol, bsdst1);
        __syncthreads();

        bf16x8 af[4], bfr[4];
#pragma unroll
        for (int mt = 0; mt < 4; ++mt)
            af[mt] = *(const bf16x8*)&As[(mw + mt * 16 + lk) * 32 + lq * 8];
#pragma unroll
        for (int nt = 0; nt < 4; ++nt)
            bfr[nt] = *(const bf16x8*)&Bs[(nw + nt * 16 + lk) * 32 + lq * 8];
#pragma unroll
        for (int mt = 0; mt < 4; ++mt)
#pragma unroll
            for (int nt = 0; nt < 4; ++nt)
                acc[mt][nt] = __builtin_amdgcn_mfma_f32_16x16x32_bf16(af[mt], bfr[nt], acc[mt][nt], 0, 0, 0);
    }

#pragma unroll
    for (int mt = 0; mt < 4; ++mt) {
#pragma unroll
        for (int nt = 0; nt < 4; ++nt) {
            const int col = n0 + nw + nt * 16 + lk;
            const float bv = bias[col];
#pragma unroll
            for (int r = 0; r < 4; ++r) {
                const int row = m0 + mw + mt * 16 + lq * 4 + r;
                outp[(size_t)row * Ndim + col] = f2bf(acc[mt][nt][r] + bv);
            }
        }
    }
}

// ---------------------------------------------------------------------------
// Proj GEMM: 64x128 tile, BK=32, grid (N/128, M/64) = 512 blocks (2/CU).
// Wave tile 32x64 (2x4 MFMA). fp32 output.
// ---------------------------------------------------------------------------
__global__ __launch_bounds__(256)
void gemm_mfma_proj(const short* __restrict__ A, const short* __restrict__ Bt,
                    const float* __restrict__ bias, float* __restrict__ outp,
                    int Ndim, int Kdim)
{
    __shared__ __align__(16) short As[64 * 32];
    __shared__ __align__(16) short Bs[128 * 32];

    const int tid = threadIdx.x;
    const int w   = tid >> 6;
    const int l   = tid & 63;
    const int lk  = l & 15;
    const int lq  = l >> 4;
    const int m0  = blockIdx.y * 64, n0 = blockIdx.x * 128;
    const int mw  = (w & 1) * 32, nw = (w >> 1) * 64;

    const int srow = w * 16 + (l >> 2);
    const int scol = (l & 3) * 8;
    short* asdst  = &As[w * 512];
    short* bsdst0 = &Bs[w * 512];
    short* bsdst1 = &Bs[2048 + w * 512];

    f32x4 acc[2][4];
#pragma unroll
    for (int i = 0; i < 2; ++i)
#pragma unroll
        for (int j = 0; j < 4; ++j) acc[i][j] = (f32x4){0.f, 0.f, 0.f, 0.f};

    for (int k0 = 0; k0 < Kdim; k0 += 32) {
        __syncthreads();
        gload_lds16(A  + (size_t)(m0 + srow)      * Kdim + k0 + scol, asdst);
        gload_lds16(Bt + (size_t)(n0 + srow)      * Kdim + k0 + scol, bsdst0);
        gload_lds16(Bt + (size_t)(n0 + 64 + srow) * Kdim + k0 + scol, bsdst1);
        __syncthreads();

        bf16x8 af[2], bfr[4];
#pragma unroll
        for (int mt = 0; mt < 2; ++mt)
            af[mt] = *(const bf16x8*)&As[(mw + mt * 16 + lk) * 32 + lq * 8];
#pragma unroll
        for (int nt = 0; nt < 4; ++nt)
            bfr[nt] = *(const bf16x8*)&Bs[(nw + nt * 16 + lk) * 32 + lq * 8];
#pragma unroll
        for (int mt = 0; mt < 2; ++mt)
#pragma unroll
            for (int nt = 0; nt < 4; ++nt)
                acc[mt][nt] = __builtin_amdgcn_mfma_f32_16x16x32_bf16(af[mt], bfr[nt], acc[mt][nt], 0, 0, 0);
    }

#pragma unroll
    for (int mt = 0; mt < 2; ++mt) {
#pragma unroll
        for (int nt = 0; nt < 4; ++nt) {
            const int col = n0 + nw + nt * 16 + lk;
            const float bv = bias[col];
#pragma unroll
            for (int r = 0; r < 4; ++r) {
                const int row = m0 + mw + mt * 16 + lq * 4 + r;
                outp[(size_t)row * Ndim + col] = acc[mt][nt][r] + bv;
            }
        }
    }
}

// ---------------------------------------------------------------------------
// MFMA flash attention v3: barrier-free single-wave blocks.
// Block = 1 wave (64 threads), 32 q-rows (2 m-tiles), key-tile 64.
// K fragments loaded directly from global (no LDS). V transposed in LDS;
// P round-trips through LDS (C-layout -> A-layout). No __syncthreads.
// Grid: 2048 blocks, XCD-partitioned: xcd=idx&7 owns bh in [xcd*4, xcd*4+4),
// qt descending (longest blocks dispatch first).
// ---------------------------------------------------------------------------
constexpr int LDV = 72;   // 64 keys + 8 pad (144 B rows, 16B-aligned)

__global__ __launch_bounds__(64)
void attn_mfma(const short* __restrict__ qkv, short* __restrict__ att)
{
    __shared__ __align__(16) short Vt[64 * LDV];   // [dim][key]  9.2 KB
    __shared__ __align__(16) short Ps[32 * LDV];   // [q][key]    4.6 KB

    const int idx = blockIdx.x;
    const int xcd = idx & 7;
    const int j   = idx >> 3;                 // 0..255
    const int bh  = xcd * 4 + (j & 3);        // 4 (b,h) pairs per XCD
    const int qt  = 63 - (j >> 2);            // longest-first
    const int b   = bh >> 4;
    const int h   = bh & 15;
    const int qbase = qt * 32;

    const int l  = threadIdx.x;
    const int lk = l & 15;
    const int lq = l >> 4;

    const short* base = qkv + (size_t)b * T * 3072 + h * 64;

    // Q A-fragments for 2 m-tiles, loaded once
    bf16x8 qf[2][2];
#pragma unroll
    for (int mq = 0; mq < 2; ++mq) {
        const short* qp = base + (size_t)(qbase + mq * 16 + lk) * 3072 + lq * 8;
        qf[mq][0] = *(const bf16x8*)qp;
        qf[mq][1] = *(const bf16x8*)(qp + 32);
    }

    f32x4 acc_o[2][4];
#pragma unroll
    for (int mq = 0; mq < 2; ++mq)
#pragma unroll
        for (int dt = 0; dt < 4; ++dt) acc_o[mq][dt] = (f32x4){0.f, 0.f, 0.f, 0.f};
    float m_r[2][4], l_r[2][4];
#pragma unroll
    for (int mq = 0; mq < 2; ++mq)
#pragma unroll
        for (int r = 0; r < 4; ++r) { m_r[mq][r] = -INFINITY; l_r[mq][r] = 0.f; }

    const int vkg = l & 15;          // V key group (4 consecutive keys)
    const int vd0 = (l >> 4) * 16;   // V dim base

    const int nkt = (qbase + 32 + 63) >> 6;
#pragma unroll 1
    for (int it = 0; it < nkt; ++it) {
        const int j0 = it * 64;

        // --- stage V transposed (wave-private; in-order DS pipe, no barrier) ---
        {
            const short* vp = base + 2048 + (size_t)(j0 + vkg * 4) * 3072 + vd0;
            bf16x8 va[4], vb[4];
#pragma unroll
            for (int kk = 0; kk < 4; ++kk) {
                va[kk] = *(const bf16x8*)(vp + kk * 3072);
                vb[kk] = *(const bf16x8*)(vp + kk * 3072 + 8);
            }
#pragma unroll
            for (int jj = 0; jj < 8; ++jj) {
                short4 p0, p1;
                p0.x = va[0][jj]; p0.y = va[1][jj]; p0.z = va[2][jj]; p0.w = va[3][jj];
                p1.x = vb[0][jj]; p1.y = vb[1][jj]; p1.z = vb[2][jj]; p1.w = vb[3][jj];
                *(short4*)&Vt[(vd0 + jj) * LDV + vkg * 4]     = p0;
                *(short4*)&Vt[(vd0 + 8 + jj) * LDV + vkg * 4] = p1;
            }
        }

        // --- S = Q K^T, K frags direct from global ---
        f32x4 s[2][4];
#pragma unroll
        for (int kt = 0; kt < 4; ++kt) {
            const short* kp = base + 1024 + (size_t)(j0 + kt * 16 + lk) * 3072 + lq * 8;
            const bf16x8 kf0 = *(const bf16x8*)kp;
            const bf16x8 kf1 = *(const bf16x8*)(kp + 32);
#pragma unroll
            for (int mq = 0; mq < 2; ++mq) {
                f32x4 a = (f32x4){0.f, 0.f, 0.f, 0.f};
                a = __builtin_amdgcn_mfma_f32_16x16x32_bf16(qf[mq][0], kf0, a, 0, 0, 0);
                a = __builtin_amdgcn_mfma_f32_16x16x32_bf16(qf[mq][1], kf1, a, 0, 0, 0);
                s[mq][kt] = a;
            }
        }

        // --- scale + causal mask ---
#pragma unroll
        for (int mq = 0; mq < 2; ++mq) {
            const int rowbase = qbase + mq * 16 + lq * 4;
            if (j0 + 63 > rowbase) {   // tile can cross diagonal for these rows
#pragma unroll
                for (int kt = 0; kt < 4; ++kt)
#pragma unroll
                    for (int r = 0; r < 4; ++r) {
                        float sv = s[mq][kt][r] * 0.125f;
                        if (j0 + kt * 16 + lk > rowbase + r) sv = -1e30f;
                        s[mq][kt][r] = sv;
                    }
            } else {
#pragma unroll
                for (int kt = 0; kt < 4; ++kt)
#pragma unroll
                    for (int r = 0; r < 4; ++r) s[mq][kt][r] *= 0.125f;
            }
        }

        // --- online softmax (rows span 16 lanes) ---
        float corr[2][4];
#pragma unroll
        for (int mq = 0; mq < 2; ++mq) {
#pragma unroll
            for (int r = 0; r < 4; ++r) {
                float mx = fmaxf(fmaxf(s[mq][0][r], s[mq][1][r]),
                                 fmaxf(s[mq][2][r], s[mq][3][r]));
                mx = fmaxf(mx, __shfl_xor(mx, 1));
                mx = fmaxf(mx, __shfl_xor(mx, 2));
                mx = fmaxf(mx, __shfl_xor(mx, 4));
                mx = fmaxf(mx, __shfl_xor(mx, 8));
                const float mn = fmaxf(m_r[mq][r], mx);
                corr[mq][r] = __expf(m_r[mq][r] - mn);
                m_r[mq][r]  = mn;
                float ps = 0.f;
#pragma unroll
                for (int kt = 0; kt < 4; ++kt) {
                    const float p = __expf(s[mq][kt][r] - mn);
                    s[mq][kt][r] = p;
                    ps += p;
                }
                ps += __shfl_xor(ps, 1);
                ps += __shfl_xor(ps, 2);
                ps += __shfl_xor(ps, 4);
                ps += __shfl_xor(ps, 8);
                l_r[mq][r] = l_r[mq][r] * corr[mq][r] + ps;
            }
        }

        // --- P: C-layout -> LDS -> A-layout; rescale O ---
#pragma unroll
        for (int mq = 0; mq < 2; ++mq) {
#pragma unroll
            for (int kt = 0; kt < 4; ++kt)
#pragma unroll
                for (int r = 0; r < 4; ++r)
                    Ps[(mq * 16 + lq * 4 + r) * LDV + kt * 16 + lk] = f2bf(s[mq][kt][r]);
#pragma unroll
            for (int dt = 0; dt < 4; ++dt)
#pragma unroll
                for (int r = 0; r < 4; ++r) acc_o[mq][dt][r] *= corr[mq][r];
        }

        // --- O += P V ---
#pragma unroll
        for (int kc = 0; kc < 2; ++kc) {
            const bf16x8 pf0 = *(const bf16x8*)&Ps[(lk) * LDV + kc * 32 + lq * 8];
            const bf16x8 pf1 = *(const bf16x8*)&Ps[(16 + lk) * LDV + kc * 32 + lq * 8];
#pragma unroll
            for (int dt = 0; dt < 4; ++dt) {
                const bf16x8 vf = *(const bf16x8*)&Vt[(dt * 16 + lk) * LDV + kc * 32 + lq * 8];
                acc_o[0][dt] = __builtin_amdgcn_mfma_f32_16x16x32_bf16(pf0, vf, acc_o[0][dt], 0, 0, 0);
                acc_o[1][dt] = __builtin_amdgcn_mfma_f32_16x16x32_bf16(pf1, vf, acc_o[1][dt], 0, 0, 0);
            }
        }
    }

    // --- epilogue ---
#pragma unroll
    for (int mq = 0; mq < 2; ++mq) {
        short* op = att + ((size_t)(b * T + qbase + mq * 16)) * 1024 + h * 64;
#pragma unroll
        for (int r = 0; r < 4; ++r) {
            const float inv = 1.f / l_r[mq][r];
#pragma unroll
            for (int dt = 0; dt < 4; ++dt)
                op[(size_t)(lq * 4 + r) * 1024 + dt * 16 + lk] = f2bf(acc_o[mq][dt][r] * inv);
        }
    }
}

// ---------------------------------------------------------------------------
extern "C" void kernel_launch(void* const* d_in, const int* in_sizes, int n_in,
                              void* d_out, int out_size, void* d_ws, size_t ws_size,
                              hipStream_t stream)
{
    const float* x      = (const float*)d_in[0];   // [B,T,C]
    const float* w_qkv  = (const float*)d_in[1];   // [C,3C]
    const float* b_qkv  = (const float*)d_in[2];   // [3C]
    const float* w_proj = (const float*)d_in[3];   // [C,C]
    const float* b_proj = (const float*)d_in[4];   // [C]
    float* out = (float*)d_out;                    // [B,T,C] fp32

    short* xb     = (short*)d_ws;                        //  8 MB
    short* wqkvt  = xb     + (size_t)M * C;              //  6 MB  [3072][1024]
    short* wprojt = wqkvt  + (size_t)NQKV * C;           //  2 MB  [1024][1024]
    short* qkvb   = wprojt + (size_t)C * C;              // 24 MB  [4096][3072]
    short* attb   = qkvb   + (size_t)M * NQKV;           //  8 MB  [4096][1024]

    cvt_bf16<<<(M * C) / 1024, 256, 0, stream>>>(x, xb, M * C);
    transpose_cvt<<<dim3(NQKV / 32, C / 32), dim3(32, 8), 0, stream>>>(w_qkv, wqkvt, C, NQKV);
    transpose_cvt<<<dim3(C / 32, C / 32), dim3(32, 8), 0, stream>>>(w_proj, wprojt, C, C);

    gemm_mfma<<<dim3(NQKV / 128, M / 128), 256, 0, stream>>>(xb, wqkvt, b_qkv, qkvb, NQKV, C);
    attn_mfma<<<2048, 64, 0, stream>>>(qkvb, attb);
    gemm_mfma_proj<<<dim3(C / 128, M / 64), 256, 0, stream>>>(attb, wprojt, b_proj, out, C, C);
}

// Round 6
// 214.070 us; speedup vs baseline: 1.3273x; 1.3273x over previous
//
#include <hip/hip_runtime.h>
#include <hip/hip_bf16.h>
#include <math.h>

// Problem constants (reference: B=2, T=2048, D_MODEL=1024, N_HEAD=16, D_HEAD=64)
constexpr int Bb   = 2;
constexpr int T    = 2048;
constexpr int C    = 1024;
constexpr int H    = 16;
constexpr int M    = Bb * T;   // 4096 rows
constexpr int NQKV = 3 * C;    // 3072

typedef __attribute__((ext_vector_type(8))) short bf16x8;
typedef __attribute__((ext_vector_type(4))) float f32x4;

__device__ inline short f2bf(float f) {
    __hip_bfloat16 h = __float2bfloat16(f);
    return *reinterpret_cast<short*>(&h);
}

#define GLOBAL_AS __attribute__((address_space(1)))
#define LDS_AS    __attribute__((address_space(3)))

__device__ __forceinline__ void gload_lds16(const short* g, short* s) {
    __builtin_amdgcn_global_load_lds((const GLOBAL_AS void*)g, (LDS_AS void*)s, 16, 0, 0);
}

// ---------------------------------------------------------------------------
// Fused prep: x->bf16 (blocks 0..4095), w_qkv transpose (4096..7167),
// w_proj transpose (7168..8191). One launch instead of three.
// ---------------------------------------------------------------------------
__global__ __launch_bounds__(256)
void prep_all(const float* __restrict__ x, short* __restrict__ xb,
              const float* __restrict__ w_qkv, short* __restrict__ wqkvt,
              const float* __restrict__ w_proj, short* __restrict__ wprojt)
{
    __shared__ float tile[32][33];
    const int blk = blockIdx.x;
    const int tid = threadIdx.x;

    if (blk < 4096) {                       // cvt x
        const int i = blk * 1024 + tid * 4;
        const float4 v = *(const float4*)(x + i);
        short4 s;
        s.x = f2bf(v.x); s.y = f2bf(v.y); s.z = f2bf(v.z); s.w = f2bf(v.w);
        *(short4*)(xb + i) = s;
        return;
    }

    const bool isqkv = (blk < 7168);
    const int bidx = isqkv ? (blk - 4096) : (blk - 7168);
    const int nblk = isqkv ? 96 : 32;       // N/32
    const int N    = isqkv ? NQKV : C;
    const float* W = isqkv ? w_qkv : w_proj;
    short* Wt      = isqkv ? wqkvt : wprojt;

    const int n0 = (bidx % nblk) * 32, k0 = (bidx / nblk) * 32;
    const int tx = tid & 31, ty = tid >> 5;   // 32 x 8
#pragma unroll
    for (int i = 0; i < 32; i += 8)
        tile[ty + i][tx] = W[(size_t)(k0 + ty + i) * N + n0 + tx];
    __syncthreads();
#pragma unroll
    for (int i = 0; i < 32; i += 8)
        Wt[(size_t)(n0 + ty + i) * C + k0 + tx] = f2bf(tile[tx][ty + i]);
}

// ---------------------------------------------------------------------------
// QKV GEMM: out[M,N] = A @ Bt^T + bias   (128x128 tile, BK=32, m97 staging)
// ---------------------------------------------------------------------------
__global__ __launch_bounds__(256)
void gemm_mfma(const short* __restrict__ A, const short* __restrict__ Bt,
               const float* __restrict__ bias, short* __restrict__ outp,
               int Ndim, int Kdim)
{
    __shared__ __align__(16) short As[128 * 32];
    __shared__ __align__(16) short Bs[128 * 32];

    const int tid = threadIdx.x;
    const int w   = tid >> 6;
    const int l   = tid & 63;
    const int lk  = l & 15;
    const int lq  = l >> 4;
    const int m0  = blockIdx.y * 128, n0 = blockIdx.x * 128;
    const int mw  = (w >> 1) * 64, nw = (w & 1) * 64;

    const int srow = w * 16 + (l >> 2);
    const int scol = (l & 3) * 8;
    short* asdst0 = &As[w * 512];
    short* asdst1 = &As[2048 + w * 512];
    short* bsdst0 = &Bs[w * 512];
    short* bsdst1 = &Bs[2048 + w * 512];

    f32x4 acc[4][4];
#pragma unroll
    for (int i = 0; i < 4; ++i)
#pragma unroll
        for (int j = 0; j < 4; ++j) acc[i][j] = (f32x4){0.f, 0.f, 0.f, 0.f};

    for (int k0 = 0; k0 < Kdim; k0 += 32) {
        __syncthreads();
        gload_lds16(A  + (size_t)(m0 + srow)      * Kdim + k0 + scol, asdst0);
        gload_lds16(A  + (size_t)(m0 + 64 + srow) * Kdim + k0 + scol, asdst1);
        gload_lds16(Bt + (size_t)(n0 + srow)      * Kdim + k0 + scol, bsdst0);
        gload_lds16(Bt + (size_t)(n0 + 64 + srow) * Kdim + k0 + scol, bsdst1);
        __syncthreads();

        bf16x8 af[4], bfr[4];
#pragma unroll
        for (int mt = 0; mt < 4; ++mt)
            af[mt] = *(const bf16x8*)&As[(mw + mt * 16 + lk) * 32 + lq * 8];
#pragma unroll
        for (int nt = 0; nt < 4; ++nt)
            bfr[nt] = *(const bf16x8*)&Bs[(nw + nt * 16 + lk) * 32 + lq * 8];
#pragma unroll
        for (int mt = 0; mt < 4; ++mt)
#pragma unroll
            for (int nt = 0; nt < 4; ++nt)
                acc[mt][nt] = __builtin_amdgcn_mfma_f32_16x16x32_bf16(af[mt], bfr[nt], acc[mt][nt], 0, 0, 0);
    }

#pragma unroll
    for (int mt = 0; mt < 4; ++mt) {
#pragma unroll
        for (int nt = 0; nt < 4; ++nt) {
            const int col = n0 + nw + nt * 16 + lk;
            const float bv = bias[col];
#pragma unroll
            for (int r = 0; r < 4; ++r) {
                const int row = m0 + mw + mt * 16 + lq * 4 + r;
                outp[(size_t)row * Ndim + col] = f2bf(acc[mt][nt][r] + bv);
            }
        }
    }
}

// ---------------------------------------------------------------------------
// Proj GEMM: 64x128 tile, BK=32, grid (8,64)=512 blocks. fp32 output.
// ---------------------------------------------------------------------------
__global__ __launch_bounds__(256)
void gemm_mfma_proj(const short* __restrict__ A, const short* __restrict__ Bt,
                    const float* __restrict__ bias, float* __restrict__ outp,
                    int Ndim, int Kdim)
{
    __shared__ __align__(16) short As[64 * 32];
    __shared__ __align__(16) short Bs[128 * 32];

    const int tid = threadIdx.x;
    const int w   = tid >> 6;
    const int l   = tid & 63;
    const int lk  = l & 15;
    const int lq  = l >> 4;
    const int m0  = blockIdx.y * 64, n0 = blockIdx.x * 128;
    const int mw  = (w & 1) * 32, nw = (w >> 1) * 64;

    const int srow = w * 16 + (l >> 2);
    const int scol = (l & 3) * 8;
    short* asdst  = &As[w * 512];
    short* bsdst0 = &Bs[w * 512];
    short* bsdst1 = &Bs[2048 + w * 512];

    f32x4 acc[2][4];
#pragma unroll
    for (int i = 0; i < 2; ++i)
#pragma unroll
        for (int j = 0; j < 4; ++j) acc[i][j] = (f32x4){0.f, 0.f, 0.f, 0.f};

    for (int k0 = 0; k0 < Kdim; k0 += 32) {
        __syncthreads();
        gload_lds16(A  + (size_t)(m0 + srow)      * Kdim + k0 + scol, asdst);
        gload_lds16(Bt + (size_t)(n0 + srow)      * Kdim + k0 + scol, bsdst0);
        gload_lds16(Bt + (size_t)(n0 + 64 + srow) * Kdim + k0 + scol, bsdst1);
        __syncthreads();

        bf16x8 af[2], bfr[4];
#pragma unroll
        for (int mt = 0; mt < 2; ++mt)
            af[mt] = *(const bf16x8*)&As[(mw + mt * 16 + lk) * 32 + lq * 8];
#pragma unroll
        for (int nt = 0; nt < 4; ++nt)
            bfr[nt] = *(const bf16x8*)&Bs[(nw + nt * 16 + lk) * 32 + lq * 8];
#pragma unroll
        for (int mt = 0; mt < 2; ++mt)
#pragma unroll
            for (int nt = 0; nt < 4; ++nt)
                acc[mt][nt] = __builtin_amdgcn_mfma_f32_16x16x32_bf16(af[mt], bfr[nt], acc[mt][nt], 0, 0, 0);
    }

#pragma unroll
    for (int mt = 0; mt < 2; ++mt) {
#pragma unroll
        for (int nt = 0; nt < 4; ++nt) {
            const int col = n0 + nw + nt * 16 + lk;
            const float bv = bias[col];
#pragma unroll
            for (int r = 0; r < 4; ++r) {
                const int row = m0 + mw + mt * 16 + lq * 4 + r;
                outp[(size_t)row * Ndim + col] = acc[mt][nt][r] + bv;
            }
        }
    }
}

// ---------------------------------------------------------------------------
// MFMA flash attention v4: 4-wave blocks, q-tile 64, key-tile 64,
// async-LDS K staging (two unpadded [64][32] half-tiles, m97 pattern),
// high occupancy (26.4 KB LDS -> 5 blocks/CU = 20 waves/CU).
// Grid: 1024 blocks; idx&7 -> XCD owns 4 bh pairs (L2-resident K/V, R5-proven);
// qt permuted so each CU's round-robin set {s,s+8,s+16,s+24} sums to 62.
// ---------------------------------------------------------------------------
constexpr int LDV = 72;   // Vt/Ps padded leading dim

__global__ __launch_bounds__(256)
void attn_mfma(const short* __restrict__ qkv, short* __restrict__ att)
{
    __shared__ __align__(16) short Ks0[64 * 32];     // keys x dims 0..31   (4 KB)
    __shared__ __align__(16) short Ks1[64 * 32];     // keys x dims 32..63  (4 KB)
    __shared__ __align__(16) short Vt[64 * LDV];     // [dim][key]          (9.2 KB)
    __shared__ __align__(16) short Ps[4][16 * LDV];  // per-wave [q][key]   (9.2 KB)

    const int idx = blockIdx.x;
    const int xcd = idx & 7;
    const int j   = idx >> 3;                // 0..127
    const int bh  = xcd * 4 + (j & 3);
    const int s   = j >> 2;                  // 0..31
    // balanced permutation: {perm(s),perm(s+8),perm(s+16),perm(s+24)} sums 62
    const int qt  = (s < 8)  ? (31 - s)
                  : (s < 16) ? (s - 8)
                  : (s < 24) ? (39 - s)
                  :            (s - 16);
    const int b   = bh >> 4;
    const int h   = bh & 15;
    const int qbase = qt * 64;

    const int tid = threadIdx.x;
    const int w   = tid >> 6;
    const int l   = tid & 63;
    const int lk  = l & 15;
    const int lq  = l >> 4;

    const short* base = qkv + (size_t)b * T * 3072 + h * 64;

    // Q A-fragments (wave w owns rows qbase + w*16 .. +16), loaded once
    const short* qp = base + (size_t)(qbase + w * 16 + lk) * 3072 + lq * 8;
    const bf16x8 qf0 = *(const bf16x8*)qp;
    const bf16x8 qf1 = *(const bf16x8*)(qp + 32);

    f32x4 acc_o[4];
#pragma unroll
    for (int dt = 0; dt < 4; ++dt) acc_o[dt] = (f32x4){0.f, 0.f, 0.f, 0.f};
    float m_r[4] = {-INFINITY, -INFINITY, -INFINITY, -INFINITY};
    float l_r[4] = {0.f, 0.f, 0.f, 0.f};

    // K staging map (per wave, async): lane i -> row w*16 + i/4, dim-chunk (i%4)*8
    const int ksrow = w * 16 + (l >> 2);
    const int kscol = (l & 3) * 8;
    short* ksdst0 = &Ks0[w * 512];
    short* ksdst1 = &Ks1[w * 512];

    // V staging map (block-wide): thread t -> keys (t&15)*4..+4, dims (t>>4)*4..+4
    const int vkg = (tid & 15) * 4;
    const int vd0 = (tid >> 4) * 4;

    const int nkt = qt + 1;
#pragma unroll 1
    for (int it = 0; it < nkt; ++it) {
        const int j0 = it * 64;
        __syncthreads();
        // K: async global->LDS, 16B/lane
        gload_lds16(base + 1024 + (size_t)(j0 + ksrow) * 3072 + kscol,      ksdst0);
        gload_lds16(base + 1024 + (size_t)(j0 + ksrow) * 3072 + 32 + kscol, ksdst1);
        // V: transpose via VGPRs, packed b64 writes
        {
            const short* vp = base + 2048 + (size_t)(j0 + vkg) * 3072 + vd0;
            short4 vr[4];
#pragma unroll
            for (int kk = 0; kk < 4; ++kk)
                vr[kk] = *(const short4*)(vp + (size_t)kk * 3072);
#pragma unroll
            for (int d = 0; d < 4; ++d) {
                short4 pk;
                pk.x = ((short*)&vr[0])[d]; pk.y = ((short*)&vr[1])[d];
                pk.z = ((short*)&vr[2])[d]; pk.w = ((short*)&vr[3])[d];
                *(short4*)&Vt[(vd0 + d) * LDV + vkg] = pk;
            }
        }
        __syncthreads();

        // --- S = Q K^T (4 key-subtiles of 16) ---
        f32x4 s4[4];
#pragma unroll
        for (int kt = 0; kt < 4; ++kt) {
            const bf16x8 kf0 = *(const bf16x8*)&Ks0[(kt * 16 + lk) * 32 + lq * 8];
            const bf16x8 kf1 = *(const bf16x8*)&Ks1[(kt * 16 + lk) * 32 + lq * 8];
            f32x4 a = (f32x4){0.f, 0.f, 0.f, 0.f};
            a = __builtin_amdgcn_mfma_f32_16x16x32_bf16(qf0, kf0, a, 0, 0, 0);
            a = __builtin_amdgcn_mfma_f32_16x16x32_bf16(qf1, kf1, a, 0, 0, 0);
            s4[kt] = a;
        }

        // --- scale + causal mask (diagonal tile only) ---
        if (it == nkt - 1) {
            const int rowbase = qbase + w * 16 + lq * 4;
#pragma unroll
            for (int kt = 0; kt < 4; ++kt)
#pragma unroll
                for (int r = 0; r < 4; ++r) {
                    float sv = s4[kt][r] * 0.125f;
                    if (j0 + kt * 16 + lk > rowbase + r) sv = -1e30f;
                    s4[kt][r] = sv;
                }
        } else {
#pragma unroll
            for (int kt = 0; kt < 4; ++kt)
#pragma unroll
                for (int r = 0; r < 4; ++r) s4[kt][r] *= 0.125f;
        }

        // --- online softmax (rows span 16 lanes) ---
        float corr[4];
#pragma unroll
        for (int r = 0; r < 4; ++r) {
            float mx = fmaxf(fmaxf(s4[0][r], s4[1][r]), fmaxf(s4[2][r], s4[3][r]));
            mx = fmaxf(mx, __shfl_xor(mx, 1));
            mx = fmaxf(mx, __shfl_xor(mx, 2));
            mx = fmaxf(mx, __shfl_xor(mx, 4));
            mx = fmaxf(mx, __shfl_xor(mx, 8));
            const float mn = fmaxf(m_r[r], mx);
            corr[r] = __expf(m_r[r] - mn);
            m_r[r]  = mn;
            float ps = 0.f;
#pragma unroll
            for (int kt = 0; kt < 4; ++kt) {
                const float p = __expf(s4[kt][r] - mn);
                s4[kt][r] = p;
                ps += p;
            }
            ps += __shfl_xor(ps, 1);
            ps += __shfl_xor(ps, 2);
            ps += __shfl_xor(ps, 4);
            ps += __shfl_xor(ps, 8);
            l_r[r] = l_r[r] * corr[r] + ps;
        }

        // --- P: C-layout -> per-wave LDS -> A-layout; rescale O ---
        short* myP = &Ps[w][0];
#pragma unroll
        for (int kt = 0; kt < 4; ++kt)
#pragma unroll
            for (int r = 0; r < 4; ++r)
                myP[(lq * 4 + r) * LDV + kt * 16 + lk] = f2bf(s4[kt][r]);
#pragma unroll
        for (int dt = 0; dt < 4; ++dt)
#pragma unroll
            for (int r = 0; r < 4; ++r) acc_o[dt][r] *= corr[r];

        // --- O += P V (64 keys as two 32-key chunks) ---
#pragma unroll
        for (int kc = 0; kc < 2; ++kc) {
            const bf16x8 pf = *(const bf16x8*)&myP[lk * LDV + kc * 32 + lq * 8];
#pragma unroll
            for (int dt = 0; dt < 4; ++dt) {
                const bf16x8 vf = *(const bf16x8*)&Vt[(dt * 16 + lk) * LDV + kc * 32 + lq * 8];
                acc_o[dt] = __builtin_amdgcn_mfma_f32_16x16x32_bf16(pf, vf, acc_o[dt], 0, 0, 0);
            }
        }
    }

    // --- epilogue: normalize, store bf16 [B,T,C] head-concat ---
    short* op = att + ((size_t)(b * T + qbase + w * 16)) * 1024 + h * 64;
#pragma unroll
    for (int r = 0; r < 4; ++r) {
        const float inv = 1.f / l_r[r];
#pragma unroll
        for (int dt = 0; dt < 4; ++dt)
            op[(size_t)(lq * 4 + r) * 1024 + dt * 16 + lk] = f2bf(acc_o[dt][r] * inv);
    }
}

// ---------------------------------------------------------------------------
extern "C" void kernel_launch(void* const* d_in, const int* in_sizes, int n_in,
                              void* d_out, int out_size, void* d_ws, size_t ws_size,
                              hipStream_t stream)
{
    const float* x      = (const float*)d_in[0];   // [B,T,C]
    const float* w_qkv  = (const float*)d_in[1];   // [C,3C]
    const float* b_qkv  = (const float*)d_in[2];   // [3C]
    const float* w_proj = (const float*)d_in[3];   // [C,C]
    const float* b_proj = (const float*)d_in[4];   // [C]
    float* out = (float*)d_out;                    // [B,T,C] fp32

    short* xb     = (short*)d_ws;                        //  8 MB
    short* wqkvt  = xb     + (size_t)M * C;              //  6 MB  [3072][1024]
    short* wprojt = wqkvt  + (size_t)NQKV * C;           //  2 MB  [1024][1024]
    short* qkvb   = wprojt + (size_t)C * C;              // 24 MB  [4096][3072]
    short* attb   = qkvb   + (size_t)M * NQKV;           //  8 MB  [4096][1024]

    prep_all<<<8192, 256, 0, stream>>>(x, xb, w_qkv, wqkvt, w_proj, wprojt);
    gemm_mfma<<<dim3(NQKV / 128, M / 128), 256, 0, stream>>>(xb, wqkvt, b_qkv, qkvb, NQKV, C);
    attn_mfma<<<1024, 256, 0, stream>>>(qkvb, attb);
    gemm_mfma_proj<<<dim3(C / 128, M / 64), 256, 0, stream>>>(attb, wprojt, b_proj, out, C, C);
}

// Round 8
// 201.392 us; speedup vs baseline: 1.4109x; 1.0629x over previous
//
#include <hip/hip_runtime.h>
#include <hip/hip_bf16.h>
#include <math.h>

// Problem constants (reference: B=2, T=2048, D_MODEL=1024, N_HEAD=16, D_HEAD=64)
constexpr int Bb   = 2;
constexpr int T    = 2048;
constexpr int C    = 1024;
constexpr int H    = 16;
constexpr int M    = Bb * T;   // 4096 rows
constexpr int NQKV = 3 * C;    // 3072

typedef __attribute__((ext_vector_type(8))) short bf16x8;
typedef __attribute__((ext_vector_type(4))) float f32x4;

__device__ inline short f2bf(float f) {
    __hip_bfloat16 h = __float2bfloat16(f);
    return *reinterpret_cast<short*>(&h);
}

#if __has_builtin(__builtin_amdgcn_exp2f)
#define EXP2(x) __builtin_amdgcn_exp2f(x)
#else
#define EXP2(x) exp2f(x)
#endif

#define GLOBAL_AS __attribute__((address_space(1)))
#define LDS_AS    __attribute__((address_space(3)))

__device__ __forceinline__ void gload_lds16(const short* g, short* s) {
    __builtin_amdgcn_global_load_lds((const GLOBAL_AS void*)g, (LDS_AS void*)s, 16, 0, 0);
}

// Drain the wave's DS queue and forbid compiler reordering of LDS ops across
// this point. Needed for the per-wave P round-trip: the write/read lane maps
// are per-lane disjoint, so without this the scheduler may hoist the ds_read
// above the ds_writes (reads stale LDS residue on iteration 0 -> race).
__device__ __forceinline__ void lds_fence_wave() {
    __asm__ __volatile__("s_waitcnt lgkmcnt(0)" ::: "memory");
}

// ---------------------------------------------------------------------------
// Fused prep: x->bf16 (blocks 0..4095), w_qkv transpose (4096..7167),
// w_proj transpose (7168..8191).
// ---------------------------------------------------------------------------
__global__ __launch_bounds__(256)
void prep_all(const float* __restrict__ x, short* __restrict__ xb,
              const float* __restrict__ w_qkv, short* __restrict__ wqkvt,
              const float* __restrict__ w_proj, short* __restrict__ wprojt)
{
    __shared__ float tile[32][33];
    const int blk = blockIdx.x;
    const int tid = threadIdx.x;

    if (blk < 4096) {                       // cvt x
        const int i = blk * 1024 + tid * 4;
        const float4 v = *(const float4*)(x + i);
        short4 s;
        s.x = f2bf(v.x); s.y = f2bf(v.y); s.z = f2bf(v.z); s.w = f2bf(v.w);
        *(short4*)(xb + i) = s;
        return;
    }

    const bool isqkv = (blk < 7168);
    const int bidx = isqkv ? (blk - 4096) : (blk - 7168);
    const int nblk = isqkv ? 96 : 32;       // N/32
    const int N    = isqkv ? NQKV : C;
    const float* W = isqkv ? w_qkv : w_proj;
    short* Wt      = isqkv ? wqkvt : wprojt;

    const int n0 = (bidx % nblk) * 32, k0 = (bidx / nblk) * 32;
    const int tx = tid & 31, ty = tid >> 5;   // 32 x 8
#pragma unroll
    for (int i = 0; i < 32; i += 8)
        tile[ty + i][tx] = W[(size_t)(k0 + ty + i) * N + n0 + tx];
    __syncthreads();
#pragma unroll
    for (int i = 0; i < 32; i += 8)
        Wt[(size_t)(n0 + ty + i) * C + k0 + tx] = f2bf(tile[tx][ty + i]);
}

// ---------------------------------------------------------------------------
// QKV GEMM: out[M,N] = A @ Bt^T + bias   (128x128 tile, BK=32, m97 staging)
// ---------------------------------------------------------------------------
__global__ __launch_bounds__(256)
void gemm_mfma(const short* __restrict__ A, const short* __restrict__ Bt,
               const float* __restrict__ bias, short* __restrict__ outp,
               int Ndim, int Kdim)
{
    __shared__ __align__(16) short As[128 * 32];
    __shared__ __align__(16) short Bs[128 * 32];

    const int tid = threadIdx.x;
    const int w   = tid >> 6;
    const int l   = tid & 63;
    const int lk  = l & 15;
    const int lq  = l >> 4;
    const int m0  = blockIdx.y * 128, n0 = blockIdx.x * 128;
    const int mw  = (w >> 1) * 64, nw = (w & 1) * 64;

    const int srow = w * 16 + (l >> 2);
    const int scol = (l & 3) * 8;
    short* asdst0 = &As[w * 512];
    short* asdst1 = &As[2048 + w * 512];
    short* bsdst0 = &Bs[w * 512];
    short* bsdst1 = &Bs[2048 + w * 512];

    f32x4 acc[4][4];
#pragma unroll
    for (int i = 0; i < 4; ++i)
#pragma unroll
        for (int j = 0; j < 4; ++j) acc[i][j] = (f32x4){0.f, 0.f, 0.f, 0.f};

    for (int k0 = 0; k0 < Kdim; k0 += 32) {
        __syncthreads();
        gload_lds16(A  + (size_t)(m0 + srow)      * Kdim + k0 + scol, asdst0);
        gload_lds16(A  + (size_t)(m0 + 64 + srow) * Kdim + k0 + scol, asdst1);
        gload_lds16(Bt + (size_t)(n0 + srow)      * Kdim + k0 + scol, bsdst0);
        gload_lds16(Bt + (size_t)(n0 + 64 + srow) * Kdim + k0 + scol, bsdst1);
        __syncthreads();

        bf16x8 af[4], bfr[4];
#pragma unroll
        for (int mt = 0; mt < 4; ++mt)
            af[mt] = *(const bf16x8*)&As[(mw + mt * 16 + lk) * 32 + lq * 8];
#pragma unroll
        for (int nt = 0; nt < 4; ++nt)
            bfr[nt] = *(const bf16x8*)&Bs[(nw + nt * 16 + lk) * 32 + lq * 8];
#pragma unroll
        for (int mt = 0; mt < 4; ++mt)
#pragma unroll
            for (int nt = 0; nt < 4; ++nt)
                acc[mt][nt] = __builtin_amdgcn_mfma_f32_16x16x32_bf16(af[mt], bfr[nt], acc[mt][nt], 0, 0, 0);
    }

#pragma unroll
    for (int mt = 0; mt < 4; ++mt) {
#pragma unroll
        for (int nt = 0; nt < 4; ++nt) {
            const int col = n0 + nw + nt * 16 + lk;
            const float bv = bias[col];
#pragma unroll
            for (int r = 0; r < 4; ++r) {
                const int row = m0 + mw + mt * 16 + lq * 4 + r;
                outp[(size_t)row * Ndim + col] = f2bf(acc[mt][nt][r] + bv);
            }
        }
    }
}

// ---------------------------------------------------------------------------
// Proj GEMM: 64x128 tile, BK=32, grid (8,64)=512 blocks. fp32 output.
// ---------------------------------------------------------------------------
__global__ __launch_bounds__(256)
void gemm_mfma_proj(const short* __restrict__ A, const short* __restrict__ Bt,
                    const float* __restrict__ bias, float* __restrict__ outp,
                    int Ndim, int Kdim)
{
    __shared__ __align__(16) short As[64 * 32];
    __shared__ __align__(16) short Bs[128 * 32];

    const int tid = threadIdx.x;
    const int w   = tid >> 6;
    const int l   = tid & 63;
    const int lk  = l & 15;
    const int lq  = l >> 4;
    const int m0  = blockIdx.y * 64, n0 = blockIdx.x * 128;
    const int mw  = (w & 1) * 32, nw = (w >> 1) * 64;

    const int srow = w * 16 + (l >> 2);
    const int scol = (l & 3) * 8;
    short* asdst  = &As[w * 512];
    short* bsdst0 = &Bs[w * 512];
    short* bsdst1 = &Bs[2048 + w * 512];

    f32x4 acc[2][4];
#pragma unroll
    for (int i = 0; i < 2; ++i)
#pragma unroll
        for (int j = 0; j < 4; ++j) acc[i][j] = (f32x4){0.f, 0.f, 0.f, 0.f};

    for (int k0 = 0; k0 < Kdim; k0 += 32) {
        __syncthreads();
        gload_lds16(A  + (size_t)(m0 + srow)      * Kdim + k0 + scol, asdst);
        gload_lds16(Bt + (size_t)(n0 + srow)      * Kdim + k0 + scol, bsdst0);
        gload_lds16(Bt + (size_t)(n0 + 64 + srow) * Kdim + k0 + scol, bsdst1);
        __syncthreads();

        bf16x8 af[2], bfr[4];
#pragma unroll
        for (int mt = 0; mt < 2; ++mt)
            af[mt] = *(const bf16x8*)&As[(mw + mt * 16 + lk) * 32 + lq * 8];
#pragma unroll
        for (int nt = 0; nt < 4; ++nt)
            bfr[nt] = *(const bf16x8*)&Bs[(nw + nt * 16 + lk) * 32 + lq * 8];
#pragma unroll
        for (int mt = 0; mt < 2; ++mt)
#pragma unroll
            for (int nt = 0; nt < 4; ++nt)
                acc[mt][nt] = __builtin_amdgcn_mfma_f32_16x16x32_bf16(af[mt], bfr[nt], acc[mt][nt], 0, 0, 0);
    }

#pragma unroll
    for (int mt = 0; mt < 2; ++mt) {
#pragma unroll
        for (int nt = 0; nt < 4; ++nt) {
            const int col = n0 + nw + nt * 16 + lk;
            const float bv = bias[col];
#pragma unroll
            for (int r = 0; r < 4; ++r) {
                const int row = m0 + mw + mt * 16 + lq * 4 + r;
                outp[(size_t)row * Ndim + col] = acc[mt][nt][r] + bv;
            }
        }
    }
}

// ---------------------------------------------------------------------------
// MFMA flash attention v5.1: S^T formulation (register softmax) + race fix.
// S^T = K·Q^T: C-layout col=lane&15 = q-row -> each lane owns ONE q-row;
// row max/sum = in-lane tree + 2 shfl hops. PV as O^T = V^T·P^T.
// P round-trip guarded by lds_fence_wave() (see comment at definition).
// 4-wave blocks, q-tile 64, key-tile 64, async K staging; grid 1024 with
// XCD-pinned bh (L2-resident K/V) and balanced qt permutation.
// ---------------------------------------------------------------------------
constexpr int LDV = 72;
constexpr int LDP = 72;
constexpr float SC = 0.18033688f;   // 0.125 * log2(e)

__global__ __launch_bounds__(256)
void attn_mfma(const short* __restrict__ qkv, short* __restrict__ att)
{
    __shared__ __align__(16) short Ks0[64 * 32];     // keys x dims 0..31   (4 KB)
    __shared__ __align__(16) short Ks1[64 * 32];     // keys x dims 32..63  (4 KB)
    __shared__ __align__(16) short Vt[64 * LDV];     // [dim][key]          (9.2 KB)
    __shared__ __align__(16) short Ps[4][16 * LDP];  // per-wave P[q][key]  (9.2 KB)

    const int idx = blockIdx.x;
    const int xcd = idx & 7;
    const int j   = idx >> 3;                // 0..127
    const int bh  = xcd * 4 + (j & 3);
    const int s   = j >> 2;                  // 0..31
    const int qt  = (s < 8)  ? (31 - s)
                  : (s < 16) ? (s - 8)
                  : (s < 24) ? (39 - s)
                  :            (s - 16);
    const int b   = bh >> 4;
    const int h   = bh & 15;
    const int qbase = qt * 64;

    const int tid = threadIdx.x;
    const int w   = tid >> 6;
    const int l   = tid & 63;
    const int lk  = l & 15;
    const int lq  = l >> 4;

    const short* base = qkv + (size_t)b * T * 3072 + h * 64;

    // Q fragments (B-operand of S^T)
    const int q_abs = qbase + w * 16 + lk;   // this lane's q-row
    const short* qp = base + (size_t)q_abs * 3072 + lq * 8;
    const bf16x8 qf0 = *(const bf16x8*)qp;
    const bf16x8 qf1 = *(const bf16x8*)(qp + 32);

    // O^T accumulators: acc[dt][r] = O^T[d=dt*16+lq*4+r][q=lk]
    f32x4 acc_o[4];
#pragma unroll
    for (int dt = 0; dt < 4; ++dt) acc_o[dt] = (f32x4){0.f, 0.f, 0.f, 0.f};
    float m_run = -INFINITY;
    float l_run = 0.f;

    // K staging map (per wave, async 16B/lane)
    const int ksrow = w * 16 + (l >> 2);
    const int kscol = (l & 3) * 8;
    short* ksdst0 = &Ks0[w * 512];
    short* ksdst1 = &Ks1[w * 512];

    // V staging map (block-wide)
    const int vkg = (tid & 15) * 4;
    const int vd0 = (tid >> 4) * 4;

    const int nkt = qt + 1;
#pragma unroll 1
    for (int it = 0; it < nkt; ++it) {
        const int j0 = it * 64;
        __syncthreads();
        gload_lds16(base + 1024 + (size_t)(j0 + ksrow) * 3072 + kscol,      ksdst0);
        gload_lds16(base + 1024 + (size_t)(j0 + ksrow) * 3072 + 32 + kscol, ksdst1);
        {
            const short* vp = base + 2048 + (size_t)(j0 + vkg) * 3072 + vd0;
            short4 vr[4];
#pragma unroll
            for (int kk = 0; kk < 4; ++kk)
                vr[kk] = *(const short4*)(vp + (size_t)kk * 3072);
#pragma unroll
            for (int d = 0; d < 4; ++d) {
                short4 pk;
                pk.x = ((short*)&vr[0])[d]; pk.y = ((short*)&vr[1])[d];
                pk.z = ((short*)&vr[2])[d]; pk.w = ((short*)&vr[3])[d];
                *(short4*)&Vt[(vd0 + d) * LDV + vkg] = pk;
            }
        }
        __syncthreads();

        // --- S^T = K Q^T: s4[kt][r] = S[key = j0 + kt*16 + lq*4 + r][q = lk] ---
        f32x4 s4[4];
#pragma unroll
        for (int kt = 0; kt < 4; ++kt) {
            const bf16x8 kf0 = *(const bf16x8*)&Ks0[(kt * 16 + lk) * 32 + lq * 8];
            const bf16x8 kf1 = *(const bf16x8*)&Ks1[(kt * 16 + lk) * 32 + lq * 8];
            f32x4 a = (f32x4){0.f, 0.f, 0.f, 0.f};
            a = __builtin_amdgcn_mfma_f32_16x16x32_bf16(kf0, qf0, a, 0, 0, 0);
            a = __builtin_amdgcn_mfma_f32_16x16x32_bf16(kf1, qf1, a, 0, 0, 0);
            s4[kt] = a;
        }

        // --- causal mask (diagonal tile only; raw scores) ---
        if (it == nkt - 1) {
#pragma unroll
            for (int kt = 0; kt < 4; ++kt)
#pragma unroll
                for (int r = 0; r < 4; ++r)
                    if (j0 + kt * 16 + lq * 4 + r > q_abs) s4[kt][r] = -1e30f;
        }

        // --- online softmax: in-lane trees + 2 shfl hops ---
        float mx0 = fmaxf(fmaxf(s4[0][0], s4[0][1]), fmaxf(s4[0][2], s4[0][3]));
        float mx1 = fmaxf(fmaxf(s4[1][0], s4[1][1]), fmaxf(s4[1][2], s4[1][3]));
        float mx2 = fmaxf(fmaxf(s4[2][0], s4[2][1]), fmaxf(s4[2][2], s4[2][3]));
        float mx3 = fmaxf(fmaxf(s4[3][0], s4[3][1]), fmaxf(s4[3][2], s4[3][3]));
        float mx  = fmaxf(fmaxf(mx0, mx1), fmaxf(mx2, mx3));
        mx = fmaxf(mx, __shfl_xor(mx, 16));
        mx = fmaxf(mx, __shfl_xor(mx, 32));
        const float mn   = fmaxf(m_run, mx);
        const float corr = EXP2((m_run - mn) * SC);
        m_run = mn;
        const float nmc = -mn * SC;
#pragma unroll
        for (int kt = 0; kt < 4; ++kt)
#pragma unroll
            for (int r = 0; r < 4; ++r)
                s4[kt][r] = EXP2(fmaf(s4[kt][r], SC, nmc));
        float ps0 = (s4[0][0] + s4[0][1]) + (s4[0][2] + s4[0][3]);
        float ps1 = (s4[1][0] + s4[1][1]) + (s4[1][2] + s4[1][3]);
        float ps2 = (s4[2][0] + s4[2][1]) + (s4[2][2] + s4[2][3]);
        float ps3 = (s4[3][0] + s4[3][1]) + (s4[3][2] + s4[3][3]);
        float ps  = (ps0 + ps1) + (ps2 + ps3);
        ps += __shfl_xor(ps, 16);
        ps += __shfl_xor(ps, 32);
        l_run = l_run * corr + ps;

        // --- P[q][key] -> per-wave LDS (packed b32 writes) ---
        short* myP = &Ps[w][0];
#pragma unroll
        for (int kt = 0; kt < 4; ++kt) {
            const unsigned int p01 = (unsigned int)(unsigned short)f2bf(s4[kt][0])
                                   | ((unsigned int)(unsigned short)f2bf(s4[kt][1]) << 16);
            const unsigned int p23 = (unsigned int)(unsigned short)f2bf(s4[kt][2])
                                   | ((unsigned int)(unsigned short)f2bf(s4[kt][3]) << 16);
            *(unsigned int*)&myP[lk * LDP + kt * 16 + lq * 4]     = p01;
            *(unsigned int*)&myP[lk * LDP + kt * 16 + lq * 4 + 2] = p23;
        }

        // RACE FIX: order the cross-lane P write->read within the wave.
        lds_fence_wave();

#pragma unroll
        for (int dt = 0; dt < 4; ++dt)
#pragma unroll
            for (int r = 0; r < 4; ++r) acc_o[dt][r] *= corr;

        // --- O^T += V^T P^T (A = Vt-frag, B = P[q][key] row-read) ---
#pragma unroll
        for (int kc = 0; kc < 2; ++kc) {
            const bf16x8 pf = *(const bf16x8*)&myP[lk * LDP + kc * 32 + lq * 8];
#pragma unroll
            for (int dt = 0; dt < 4; ++dt) {
                const bf16x8 vf = *(const bf16x8*)&Vt[(dt * 16 + lk) * LDV + kc * 32 + lq * 8];
                acc_o[dt] = __builtin_amdgcn_mfma_f32_16x16x32_bf16(vf, pf, acc_o[dt], 0, 0, 0);
            }
        }
    }

    // --- epilogue: O[q][d] = O^T[d][q]/l; lane writes 4 contiguous d per dt ---
    const float inv = 1.f / l_run;
    short* op = att + ((size_t)(b * T + q_abs)) * 1024 + h * 64;
#pragma unroll
    for (int dt = 0; dt < 4; ++dt) {
        short4 pk;
        pk.x = f2bf(acc_o[dt][0] * inv);
        pk.y = f2bf(acc_o[dt][1] * inv);
        pk.z = f2bf(acc_o[dt][2] * inv);
        pk.w = f2bf(acc_o[dt][3] * inv);
        *(short4*)(op + dt * 16 + lq * 4) = pk;
    }
}

// ---------------------------------------------------------------------------
extern "C" void kernel_launch(void* const* d_in, const int* in_sizes, int n_in,
                              void* d_out, int out_size, void* d_ws, size_t ws_size,
                              hipStream_t stream)
{
    const float* x      = (const float*)d_in[0];   // [B,T,C]
    const float* w_qkv  = (const float*)d_in[1];   // [C,3C]
    const float* b_qkv  = (const float*)d_in[2];   // [3C]
    const float* w_proj = (const float*)d_in[3];   // [C,C]
    const float* b_proj = (const float*)d_in[4];   // [C]
    float* out = (float*)d_out;                    // [B,T,C] fp32

    short* xb     = (short*)d_ws;                        //  8 MB
    short* wqkvt  = xb     + (size_t)M * C;              //  6 MB  [3072][1024]
    short* wprojt = wqkvt  + (size_t)NQKV * C;           //  2 MB  [1024][1024]
    short* qkvb   = wprojt + (size_t)C * C;              // 24 MB  [4096][3072]
    short* attb   = qkvb   + (size_t)M * NQKV;           //  8 MB  [4096][1024]

    prep_all<<<8192, 256, 0, stream>>>(x, xb, w_qkv, wqkvt, w_proj, wprojt);
    gemm_mfma<<<dim3(NQKV / 128, M / 128), 256, 0, stream>>>(xb, wqkvt, b_qkv, qkvb, NQKV, C);
    attn_mfma<<<1024, 256, 0, stream>>>(qkvb, attb);
    gemm_mfma_proj<<<dim3(C / 128, M / 64), 256, 0, stream>>>(attb, wprojt, b_proj, out, C, C);
}